// Round 1
// baseline (691.225 us; speedup 1.0000x reference)
//
#include <hip/hip_runtime.h>
#include <math.h>

#define NN 100000
#define NE 3200000

constexpr int BLK = 256;
constexpr int GRID_EDGE = 2048;

// ws layout (floats):
//   [0:32)    stats: sum[16], sumsq[16]      (memset to 0 each launch)
//   [64:96)   scale[16], shift[16]
//   [256:...) p1 (NN*16), then p2 (NN*16)
// total need = (256 + 2*NN*16)*4 bytes ~= 12.8 MB

__device__ __forceinline__ void matvec16_acc(const float* __restrict__ sW,
                                             const float v[16], float acc[16]) {
  // acc[j] += sum_k v[k] * W[j][k]   (W row-major 16x16 in LDS, 16B-aligned)
#pragma unroll
  for (int j = 0; j < 16; ++j) {
    float a = acc[j];
#pragma unroll
    for (int q = 0; q < 4; ++q) {
      float4 w = ((const float4*)(sW + j * 16))[q];  // wave-uniform ds_read_b128
      a = fmaf(v[q * 4 + 0], w.x, a);
      a = fmaf(v[q * 4 + 1], w.y, a);
      a = fmaf(v[q * 4 + 2], w.z, a);
      a = fmaf(v[q * 4 + 3], w.w, a);
    }
    acc[j] = a;
  }
}

__device__ __forceinline__ void load_row16(const float* __restrict__ base,
                                           size_t row, float v[16]) {
  const float4* r = (const float4*)(base + row * 16);
#pragma unroll
  for (int q = 0; q < 4; ++q) {
    float4 t = r[q];
    v[q * 4 + 0] = t.x; v[q * 4 + 1] = t.y;
    v[q * 4 + 2] = t.z; v[q * 4 + 3] = t.w;
  }
}

__global__ __launch_bounds__(BLK)
void node_proj(const float* __restrict__ x, const float* __restrict__ W1,
               const float* __restrict__ W2, float* __restrict__ p1,
               float* __restrict__ p2) {
  __shared__ __align__(16) float sW1[256];
  __shared__ __align__(16) float sW2[256];
  for (int i = threadIdx.x; i < 256; i += BLK) { sW1[i] = W1[i]; sW2[i] = W2[i]; }
  __syncthreads();
  int n = blockIdx.x * BLK + threadIdx.x;
  if (n >= NN) return;
  float xv[16];
  load_row16(x, (size_t)n, xv);
  float y1[16], y2[16];
#pragma unroll
  for (int j = 0; j < 16; ++j) { y1[j] = 0.f; y2[j] = 0.f; }
  matvec16_acc(sW1, xv, y1);
  matvec16_acc(sW2, xv, y2);
  float4* o1 = (float4*)(p1 + (size_t)n * 16);
  float4* o2 = (float4*)(p2 + (size_t)n * 16);
#pragma unroll
  for (int q = 0; q < 4; ++q) {
    o1[q] = make_float4(y1[q * 4 + 0], y1[q * 4 + 1], y1[q * 4 + 2], y1[q * 4 + 3]);
    o2[q] = make_float4(y2[q * 4 + 0], y2[q * 4 + 1], y2[q * 4 + 2], y2[q * 4 + 3]);
  }
}

// PASS2 == false: accumulate per-channel sum / sumsq of e into stats (atomic).
// PASS2 == true : recompute e, apply scale/shift + relu + residual, write out.
template <bool USE_PRE, bool PASS2>
__global__ __launch_bounds__(BLK)
void edge_kernel(const float* __restrict__ ea, const int* __restrict__ ei,
                 const float* __restrict__ xO, const float* __restrict__ p1,
                 const float* __restrict__ p2, const float* __restrict__ W0g,
                 const float* __restrict__ W1g, const float* __restrict__ W2g,
                 float* __restrict__ stats, const float* __restrict__ ssg,
                 float* __restrict__ out) {
  __shared__ __align__(16) float sW0[256];
  __shared__ __align__(16) float sW1[256];
  __shared__ __align__(16) float sW2[256];
  __shared__ float sSS[32];
  __shared__ float red[4][32];
  for (int i = threadIdx.x; i < 256; i += BLK) {
    sW0[i] = W0g[i];
    if (!USE_PRE) { sW1[i] = W1g[i]; sW2[i] = W2g[i]; }
  }
  if (PASS2 && threadIdx.x < 32) sSS[threadIdx.x] = ssg[threadIdx.x];
  __syncthreads();

  float sum[16], ssq[16];
  if (!PASS2) {
#pragma unroll
    for (int j = 0; j < 16; ++j) { sum[j] = 0.f; ssq[j] = 0.f; }
  }

  const int total = gridDim.x * BLK;
  for (int e = blockIdx.x * BLK + threadIdx.x; e < NE; e += total) {
    int s = ei[e];
    int d = ei[NE + e];
    float eav[16];
    load_row16(ea, (size_t)e, eav);
    float ev[16];
    if (USE_PRE) {
      const float4* r1 = (const float4*)(p1 + (size_t)s * 16);
      const float4* r2 = (const float4*)(p2 + (size_t)d * 16);
#pragma unroll
      for (int q = 0; q < 4; ++q) {
        float4 a = r1[q];
        float4 b = r2[q];
        ev[q * 4 + 0] = a.x + b.x; ev[q * 4 + 1] = a.y + b.y;
        ev[q * 4 + 2] = a.z + b.z; ev[q * 4 + 3] = a.w + b.w;
      }
      matvec16_acc(sW0, eav, ev);
    } else {
      float xs[16], xd[16];
      load_row16(xO, (size_t)s, xs);
      load_row16(xO, (size_t)d, xd);
#pragma unroll
      for (int j = 0; j < 16; ++j) ev[j] = 0.f;
      matvec16_acc(sW0, eav, ev);
      matvec16_acc(sW1, xs, ev);
      matvec16_acc(sW2, xd, ev);
    }
    if (!PASS2) {
#pragma unroll
      for (int j = 0; j < 16; ++j) {
        sum[j] += ev[j];
        ssq[j] = fmaf(ev[j], ev[j], ssq[j]);
      }
    } else {
      float4* orow = (float4*)(out + (size_t)e * 16);
#pragma unroll
      for (int q = 0; q < 4; ++q) {
        float4 o;
        o.x = eav[q*4+0] + fmaxf(0.f, fmaf(ev[q*4+0], sSS[q*4+0], sSS[16+q*4+0]));
        o.y = eav[q*4+1] + fmaxf(0.f, fmaf(ev[q*4+1], sSS[q*4+1], sSS[16+q*4+1]));
        o.z = eav[q*4+2] + fmaxf(0.f, fmaf(ev[q*4+2], sSS[q*4+2], sSS[16+q*4+2]));
        o.w = eav[q*4+3] + fmaxf(0.f, fmaf(ev[q*4+3], sSS[q*4+3], sSS[16+q*4+3]));
        orow[q] = o;
      }
    }
  }

  if (!PASS2) {
#pragma unroll
    for (int off = 32; off > 0; off >>= 1) {
#pragma unroll
      for (int j = 0; j < 16; ++j) {
        sum[j] += __shfl_down(sum[j], off);
        ssq[j] += __shfl_down(ssq[j], off);
      }
    }
    int wid = threadIdx.x >> 6;
    int lane = threadIdx.x & 63;
    if (lane == 0) {
#pragma unroll
      for (int j = 0; j < 16; ++j) {
        red[wid][j] = sum[j];
        red[wid][16 + j] = ssq[j];
      }
    }
    __syncthreads();
    if (threadIdx.x < 32) {
      float v = red[0][threadIdx.x] + red[1][threadIdx.x] +
                red[2][threadIdx.x] + red[3][threadIdx.x];
      atomicAdd(stats + threadIdx.x, v);
    }
  }
}

__global__ void finalize_kernel(const float* __restrict__ stats,
                                const float* __restrict__ gamma,
                                const float* __restrict__ beta,
                                float* __restrict__ ss) {
  int j = threadIdx.x;
  if (j < 16) {
    const float inv_n = 1.0f / (float)NE;
    float mean = stats[j] * inv_n;
    float var = fmaf(-mean, mean, stats[16 + j] * inv_n);
    float sc = gamma[j] / sqrtf(var + 1e-5f);
    ss[j] = sc;
    ss[16 + j] = fmaf(-mean, sc, beta[j]);
  }
}

extern "C" void kernel_launch(void* const* d_in, const int* in_sizes, int n_in,
                              void* d_out, int out_size, void* d_ws, size_t ws_size,
                              hipStream_t stream) {
  const float* x     = (const float*)d_in[0];
  const int*   ei    = (const int*)d_in[1];
  const float* ea    = (const float*)d_in[2];
  const float* W0    = (const float*)d_in[3];
  const float* W1    = (const float*)d_in[5];
  const float* W2    = (const float*)d_in[7];
  const float* gamma = (const float*)d_in[9];
  const float* beta  = (const float*)d_in[10];
  float* out = (float*)d_out;

  float* ws    = (float*)d_ws;
  float* stats = ws;        // 32 floats
  float* ss    = ws + 64;   // 32 floats
  float* p1    = ws + 256;
  float* p2    = p1 + (size_t)NN * 16;
  size_t need = (256 + 2 * (size_t)NN * 16) * sizeof(float);
  bool use_pre = ws_size >= need;

  hipMemsetAsync(stats, 0, 32 * sizeof(float), stream);

  if (use_pre) {
    node_proj<<<(NN + BLK - 1) / BLK, BLK, 0, stream>>>(x, W1, W2, p1, p2);
    edge_kernel<true, false><<<GRID_EDGE, BLK, 0, stream>>>(
        ea, ei, x, p1, p2, W0, W1, W2, stats, nullptr, out);
  } else {
    edge_kernel<false, false><<<GRID_EDGE, BLK, 0, stream>>>(
        ea, ei, x, p1, p2, W0, W1, W2, stats, nullptr, out);
  }

  finalize_kernel<<<1, 64, 0, stream>>>(stats, gamma, beta, ss);

  if (use_pre) {
    edge_kernel<true, true><<<GRID_EDGE, BLK, 0, stream>>>(
        ea, ei, x, p1, p2, W0, W1, W2, stats, ss, out);
  } else {
    edge_kernel<false, true><<<GRID_EDGE, BLK, 0, stream>>>(
        ea, ei, x, p1, p2, W0, W1, W2, stats, ss, out);
  }
}